// Round 13
// baseline (184.821 us; speedup 1.0000x reference)
//
#include <hip/hip_runtime.h>

// LightGCN layer: out[d] = in_deg[d]^-1/2 * sum_{e:dst[e]=d} x[src[e]] * out_deg[src[e]]^-1/2
//
// Round 13: statically-chunked partition. Instead of histogram+reserve+scatter
// (4 LDS atomics + 2 returning global atomics per edge-block), each (partition,
// block) pair owns a fixed 48-entry chunk: single pass, 1 LDS cursor atomic +
// 1 store per side per edge. Chunk overflow (P ~ 1e-14 per chunk) reuses the
// povf/sovf machinery integrated by bincnt (R12). bincnt reads chunks
// wave-per-chunk (cnt<=48<64 lanes).
// Gather: R12 unchanged (line-rate floor ~44 us, 53 G lines/s measured).

#define D_FEAT 96
#define CAP 64
#define PART_SHIFT 8
#define PNODES 256
#define NP_MAX 256
#define EPB 3328            // 13*256; 800k edges -> 241 blocks (<=256)
#define CHK 48              // entries per (partition, block) chunk
#define OVF_CAP 8192

__device__ __forceinline__ unsigned short f2bf_rne(float f) {
    unsigned u = __float_as_uint(f);
    unsigned r = (u >> 16) & 1u;
    u += 0x7fffu + r;
    return (unsigned short)(u >> 16);
}

// ---------------- pass 1: single-pass chunked partition ----------------

__global__ __launch_bounds__(256) void partition_kernel(
        const int* __restrict__ src, const int* __restrict__ dst,
        int n_edges, int np, int nblk,
        int* __restrict__ counts_d, int* __restrict__ counts_s,   // [np*nblk]
        unsigned* __restrict__ pbuf_d,                            // [np*nblk*CHK]
        unsigned short* __restrict__ pbuf_s,                      // [np*nblk*CHK]
        int* __restrict__ ctr,            // [0]=ovf_n [1]=povf_n [2]=sovf_n
        int* __restrict__ povf_d, int* __restrict__ sovf_d) {
    __shared__ int od[NP_MAX], os_[NP_MAX];
    const int blk = blockIdx.x;
    const int base = blk * EPB;
    const int end = min(base + EPB, n_edges);

    for (int i = threadIdx.x; i < NP_MAX; i += 256) { od[i] = 0; os_[i] = 0; }
    __syncthreads();

    for (int i = base + (int)threadIdx.x; i < end; i += 256) {
        int s = src[i], d = dst[i];
        unsigned pv = (unsigned)d | ((unsigned)s << 16);
        int pd = d >> PART_SHIFT;
        int pos = atomicAdd(&od[pd], 1);
        if (pos < CHK) pbuf_d[((size_t)pd * nblk + blk) * CHK + pos] = pv;
        else { int k = atomicAdd(&ctr[1], 1); if (k < OVF_CAP) povf_d[k] = (int)pv; }
        int ps = s >> PART_SHIFT;
        int pos2 = atomicAdd(&os_[ps], 1);
        if (pos2 < CHK) pbuf_s[((size_t)ps * nblk + blk) * CHK + pos2] = (unsigned short)s;
        else { int k = atomicAdd(&ctr[2], 1); if (k < OVF_CAP) sovf_d[k] = s; }
    }
    __syncthreads();

    for (int p = threadIdx.x; p < np; p += 256) {
        int cd = od[p];  counts_d[p * nblk + blk] = cd < CHK ? cd : CHK;
        int cs = os_[p]; counts_s[p * nblk + blk] = cs < CHK ? cs : CHK;
    }
}

// ---- pass 2: bin dst + count src + integrate povf/sovf + convert (fused) ----

__global__ __launch_bounds__(256) void bincnt_kernel(
        const unsigned* __restrict__ pbuf_d, const int* __restrict__ counts_d,
        const unsigned short* __restrict__ pbuf_s, const int* __restrict__ counts_s,
        int nblk, int n_nodes,
        const float* __restrict__ x, unsigned* __restrict__ xs,
        int* __restrict__ cursor, int* __restrict__ out_cnt,
        unsigned short* __restrict__ slots,
        int* __restrict__ ctr,
        const int* __restrict__ povf_d, const int* __restrict__ sovf_d,
        int* __restrict__ ovf_d) {
    __shared__ unsigned short lslots[PNODES * CAP];   // 32 KB
    __shared__ int lcnt[PNODES];
    __shared__ int lout[PNODES];
    const int b = blockIdx.x;
    const int nbase = b << PART_SHIFT;
    const int nloc = min(PNODES, n_nodes - nbase);
    const int wid  = threadIdx.x >> 6;
    const int lane = threadIdx.x & 63;

    for (int i = threadIdx.x; i < PNODES; i += 256) { lcnt[i] = 0; lout[i] = 0; }
    __syncthreads();

    // dst side: wave w handles chunks w, w+4, ... (cnt <= 48 < 64 lanes)
    for (int c = wid; c < nblk; c += 4) {
        int cnt = __builtin_amdgcn_readfirstlane(counts_d[b * nblk + c]);
        if (lane < cnt) {
            unsigned pv = pbuf_d[((size_t)b * nblk + c) * CHK + lane];
            int dl = (int)(pv & 0xffu);
            int pos = atomicAdd(&lcnt[dl], 1);
            if (pos < CAP) lslots[dl * CAP + pos] = (unsigned short)(pv >> 16);
            else { int k = atomicAdd(&ctr[0], 1); if (k < OVF_CAP) ovf_d[k] = (int)pv; }
        }
    }
    // src side: histogram out-degree
    for (int c = wid; c < nblk; c += 4) {
        int cnt = __builtin_amdgcn_readfirstlane(counts_s[b * nblk + c]);
        if (lane < cnt) {
            int s = (int)pbuf_s[((size_t)b * nblk + c) * CHK + lane];
            atomicAdd(&lout[s & (PNODES - 1)], 1);
        }
    }
    // integrate chunk-overflow entries for THIS node range (normally empty)
    int npv = ctr[1];
    if (npv > 0) {
        if (npv > OVF_CAP) npv = OVF_CAP;
        for (int i = threadIdx.x; i < npv; i += 256) {
            unsigned pv = (unsigned)povf_d[i];
            int d = (int)(pv & 0xffffu);
            if ((d >> PART_SHIFT) == b) {
                int dl = d & (PNODES - 1);
                int pos = atomicAdd(&lcnt[dl], 1);
                if (pos < CAP) lslots[dl * CAP + pos] = (unsigned short)(pv >> 16);
                else { int k = atomicAdd(&ctr[0], 1); if (k < OVF_CAP) ovf_d[k] = (int)pv; }
            }
        }
    }
    int nsv = ctr[2];
    if (nsv > 0) {
        if (nsv > OVF_CAP) nsv = OVF_CAP;
        for (int i = threadIdx.x; i < nsv; i += 256) {
            int s = sovf_d[i];
            if ((s >> PART_SHIFT) == b) atomicAdd(&lout[s & (PNODES - 1)], 1);
        }
    }
    __syncthreads();

    for (int i = threadIdx.x; i < nloc; i += 256) {
        cursor[nbase + i]  = lcnt[i];
        out_cnt[nbase + i] = lout[i];
    }
    // slot tile write-out (coalesced)
    const unsigned* ls = (const unsigned*)lslots;
    unsigned* gs = (unsigned*)slots + (size_t)nbase * (CAP / 2);
    const int ncopy = nloc * (CAP / 2);
    for (int i = threadIdx.x; i < ncopy; i += 256) gs[i] = ls[i];

    // convert this block's x rows -> pre-scaled bf16 xs (float4 granular)
    const int ntot = nloc * 24;                 // 24 float4 per 96-feat row
    for (int i = threadIdx.x; i < ntot; i += 256) {
        int nd = i / 24;
        int j  = i - nd * 24;
        int c  = lout[nd];
        float w = rsqrtf((float)(c < 1 ? 1 : c));
        float4 vv = ((const float4*)(x + (size_t)(nbase + nd) * D_FEAT))[j];
        unsigned lo0 = f2bf_rne(vv.x * w), hi0 = f2bf_rne(vv.y * w);
        unsigned lo1 = f2bf_rne(vv.z * w), hi1 = f2bf_rne(vv.w * w);
        uint2 o;
        o.x = lo0 | (hi0 << 16);
        o.y = lo1 | (hi1 << 16);
        ((uint2*)(xs + (size_t)(nbase + nd) * 48))[j] = o;
    }
}

// ---------------- gather: wave per node, 16-deep unrolled, self-serve ovf ----

__global__ __launch_bounds__(256) void gather_kernel(
        const unsigned* __restrict__ xs,
        const unsigned short* __restrict__ slots,
        const int* __restrict__ cursor,
        const float* __restrict__ x,
        const int* __restrict__ out_cnt,
        const int* __restrict__ ctr,
        const int* __restrict__ ovf_d,
        float* __restrict__ out, int n_nodes) {
    int wid  = threadIdx.x >> 6;
    int lane = threadIdx.x & 63;
    int node = __builtin_amdgcn_readfirstlane(blockIdx.x * 4 + wid);
    if (node >= n_nodes) return;

    int cnt_all = __builtin_amdgcn_readfirstlane(cursor[node]);
    int cnt = cnt_all < CAP ? cnt_all : CAP;

    float accx = 0.f, accy = 0.f;
    const bool act = lane < 48;        // 48 lanes x (2 bf16) = 96 features

    if (cnt > 0) {
        int idx  = lane < cnt ? lane : cnt - 1;
        int sval = (int)slots[node * CAP + idx];   // lane l holds slot l's src id

        int e = 0;
        for (; e + 16 <= cnt; e += 16) {
            if (act) {
                unsigned u[16];
                #pragma unroll
                for (int k = 0; k < 16; ++k) {
                    int s = __builtin_amdgcn_readlane(sval, e + k);
                    u[k] = xs[s * 48 + lane];
                }
                #pragma unroll
                for (int k = 0; k < 16; ++k) {
                    accx += __uint_as_float(u[k] << 16);
                    accy += __uint_as_float(u[k] & 0xffff0000u);
                }
            }
        }
        for (; e + 4 <= cnt; e += 4) {
            if (act) {
                unsigned u[4];
                #pragma unroll
                for (int k = 0; k < 4; ++k) {
                    int s = __builtin_amdgcn_readlane(sval, e + k);
                    u[k] = xs[s * 48 + lane];
                }
                #pragma unroll
                for (int k = 0; k < 4; ++k) {
                    accx += __uint_as_float(u[k] << 16);
                    accy += __uint_as_float(u[k] & 0xffff0000u);
                }
            }
        }
        for (; e < cnt; ++e) {
            if (act) {
                int s = __builtin_amdgcn_readlane(sval, e);
                unsigned u0 = xs[s * 48 + lane];
                accx += __uint_as_float(u0 << 16);
                accy += __uint_as_float(u0 & 0xffff0000u);
            }
        }
    }

    // self-service overflow: only nodes with in-degree > CAP (normally none)
    if (cnt_all > CAP) {
        int novf = __builtin_amdgcn_readfirstlane(ctr[0]);
        if (novf > OVF_CAP) novf = OVF_CAP;
        for (int k = 0; k < novf; ++k) {
            unsigned pv = (unsigned)ovf_d[k];
            if ((int)(pv & 0xffffu) == node) {
                int s = (int)(pv >> 16);
                int c = out_cnt[s];
                float w = rsqrtf((float)(c < 1 ? 1 : c));
                if (act) {
                    accx += w * x[(size_t)s * D_FEAT + lane * 2];
                    accy += w * x[(size_t)s * D_FEAT + lane * 2 + 1];
                }
            }
        }
    }

    float sc = rsqrtf((float)(cnt_all < 1 ? 1 : cnt_all));
    if (act) {
        float* op = out + (size_t)node * D_FEAT + lane * 2;
        op[0] = accx * sc;
        op[1] = accy * sc;
    }
}

// ---------------- fallback (round-1 atomic scatter, any size) ----------------

__global__ void degree_kernel(const int* __restrict__ src,
                              const int* __restrict__ dst,
                              int* __restrict__ out_cnt,
                              int* __restrict__ in_cnt, int n_edges) {
    int i = blockIdx.x * blockDim.x + threadIdx.x;
    if (i < n_edges) {
        atomicAdd(&out_cnt[src[i]], 1);
        atomicAdd(&in_cnt[dst[i]], 1);
    }
}

__global__ void scale_kernel(float* __restrict__ osc, float* __restrict__ isc, int n) {
    int i = blockIdx.x * blockDim.x + threadIdx.x;
    if (i < n) {
        int c0 = ((const int*)osc)[i];
        int c1 = ((const int*)isc)[i];
        osc[i] = rsqrtf((float)(c0 < 1 ? 1 : c0));
        isc[i] = rsqrtf((float)(c1 < 1 ? 1 : c1));
    }
}

__global__ void scatter_kernel(const float* __restrict__ x,
                               const int* __restrict__ src,
                               const int* __restrict__ dst,
                               const float* __restrict__ osc,
                               const float* __restrict__ isc,
                               float* __restrict__ out, int n_edges) {
    int idx = blockIdx.x * blockDim.x + threadIdx.x;
    int e = idx / 24, c = idx % 24;
    if (e >= n_edges) return;
    int s = src[e], d = dst[e];
    float w = osc[s] * isc[d];
    const float4 v = *(const float4*)(x + (size_t)s * D_FEAT + c * 4);
    float* o = out + (size_t)d * D_FEAT + c * 4;
    unsafeAtomicAdd(o + 0, v.x * w);
    unsafeAtomicAdd(o + 1, v.y * w);
    unsafeAtomicAdd(o + 2, v.z * w);
    unsafeAtomicAdd(o + 3, v.w * w);
}

// ---------------- launcher ----------------

extern "C" void kernel_launch(void* const* d_in, const int* in_sizes, int n_in,
                              void* d_out, int out_size, void* d_ws, size_t ws_size,
                              hipStream_t stream) {
    const float* x  = (const float*)d_in[0];
    const int* src  = (const int*)d_in[1];
    const int* dst  = (const int*)d_in[2];
    float* out      = (float*)d_out;

    const int n_edges = in_sizes[1];
    const int n_nodes = in_sizes[0] / D_FEAT;

    const int np = (n_nodes + PNODES - 1) / PNODES;
    const int nblk = (n_edges + EPB - 1) / EPB;

    const size_t chunks      = (size_t)np * nblk;
    const size_t pbuf_words  = chunks * CHK;                 // dst buffer (uint)
    const size_t pbufs_words = (pbuf_words + 1) / 2;         // src buffer (ushort)

    // ws layout (int32 units). First 256 ints zeroed each call:
    int* ctr      = (int*)d_ws;           // 3 (pad to 256)
    int* ovf_d    = ctr + 256;            // OVF_CAP (packed v)
    int* povf_d   = ovf_d + OVF_CAP;      // OVF_CAP
    int* sovf_d   = povf_d + OVF_CAP;     // OVF_CAP
    int* out_cnt  = sovf_d + OVF_CAP;     // 65536
    int* cursor   = out_cnt + 65536;      // 65536
    int* counts_d = cursor + 65536;       // chunks
    int* counts_s = counts_d + chunks;    // chunks
    unsigned* pbuf_dst = (unsigned*)(counts_s + chunks);
    unsigned short* pbuf_src = (unsigned short*)(pbuf_dst + pbuf_words);
    unsigned* xs = pbuf_dst + pbuf_words + pbufs_words;
    unsigned short* slots = (unsigned short*)(xs + (size_t)n_nodes * 48);

    const size_t needed = ((size_t)256 + 3 * OVF_CAP + 2 * 65536 + 2 * chunks +
                           pbuf_words + pbufs_words + (size_t)n_nodes * 48 +
                           (size_t)n_nodes * (CAP / 2)) * 4;

    if (ws_size >= needed && n_nodes <= 65536 && np <= NP_MAX && nblk <= 256) {
        (void)hipMemsetAsync(d_ws, 0, 256 * sizeof(int), stream);

        partition_kernel<<<nblk, 256, 0, stream>>>(
            src, dst, n_edges, np, nblk, counts_d, counts_s,
            pbuf_dst, pbuf_src, ctr, povf_d, sovf_d);

        bincnt_kernel<<<np, 256, 0, stream>>>(
            pbuf_dst, counts_d, pbuf_src, counts_s, nblk, n_nodes,
            x, xs, cursor, out_cnt, slots, ctr, povf_d, sovf_d, ovf_d);

        gather_kernel<<<(n_nodes + 3) / 4, 256, 0, stream>>>(
            xs, slots, cursor, x, out_cnt, ctr, ovf_d, out, n_nodes);
    } else {
        // fallback: atomic scatter (round-1 path, any size)
        float* osc = (float*)d_ws;
        float* isc = osc + 65536;
        (void)hipMemsetAsync(d_ws, 0, 2 * 65536 * sizeof(int), stream);
        (void)hipMemsetAsync(d_out, 0, (size_t)out_size * sizeof(float), stream);
        degree_kernel<<<(n_edges + 255) / 256, 256, 0, stream>>>(
            src, dst, (int*)osc, (int*)isc, n_edges);
        scale_kernel<<<(n_nodes + 255) / 256, 256, 0, stream>>>(osc, isc, n_nodes);
        const int total = n_edges * 24;
        scatter_kernel<<<(total + 255) / 256, 256, 0, stream>>>(
            x, src, dst, osc, isc, out, n_edges);
    }
}